// Round 21
// baseline (130.871 us; speedup 1.0000x reference)
//
#include <hip/hip_runtime.h>
#include <hip/hip_bf16.h>

constexpr int NB  = 8;
constexpr int TD  = 128;
constexpr int HID = 64;
constexpr int ROWS = 128;   // tile unchanged; now 8 waves (512 thr) per block

typedef __attribute__((ext_vector_type(8))) short bf16x8;
typedef __attribute__((ext_vector_type(4))) float f32x4;

union U { unsigned u[4]; bf16x8 v; };

__device__ __forceinline__ unsigned int pk2(float a, float b) {
    __hip_bfloat162 h = __float22bfloat162_rn(float2{a, b});   // v_cvt_pk_bf16_f32 (RNE)
    unsigned int u; __builtin_memcpy(&u, &h, 4); return u;
}

// branch-free GELU: erf via Abramowitz-Stegun 7.1.26 (|err| < 1.5e-7)
__device__ __forceinline__ float gelu_fast(float x) {
    const float u = x * 0.70710678118f;
    const float a = fabsf(u);
    const float t = __builtin_amdgcn_rcpf(fmaf(0.3275911f, a, 1.0f));
    float p = fmaf(t, 1.061405429f, -1.453152027f);
    p = fmaf(t, p, 1.421413741f);
    p = fmaf(t, p, -0.284496736f);
    p = fmaf(t, p, 0.254829592f);
    p = p * t;
    const float e  = __builtin_amdgcn_exp2f(-a * a * 1.44269504f);
    const float pe = p * e;
    const float s  = (u >= 0.f) ? (2.0f - pe) : pe;   // 1 + erf(u)
    return 0.5f * x * s;
}

// ws layout (u32 pairs): [0,8192) mixW ; [8192,10240) W2 ; [10240,10496) W1 ; [10496,10752) W3
constexpr size_t WS_NEED_BYTES = 10752 * 4;

__global__ __launch_bounds__(256, 1)
void cvt_weights(const float* __restrict__ W1, const float* __restrict__ W2,
                 const float* __restrict__ W3, const float* __restrict__ mixW,
                 unsigned* __restrict__ ws)
{
    const int t = threadIdx.x;
#pragma unroll
    for (int i = 0; i < 32; ++i) {                 // mixW -> Wm[c][f], c=i*16+d, f=j*16+k
        const int p = t + i * 256;
        const int o = 2 * p;
        const int c = o >> 7, f = o & 127;
        const int ii = c >> 4, d = c & 15, j = f >> 4, k = f & 15;
        const float2 v = *(const float2*)(mixW + ii * 2048 + j * 256 + d * 16 + k);
        ws[p] = pk2(v.x, v.y);
    }
#pragma unroll
    for (int i = 0; i < 8; ++i) {                  // W2 row-major 64x64
        const int p = t + i * 256;
        const float2 v = *(const float2*)(W2 + 2 * p);
        ws[8192 + p] = pk2(v.x, v.y);
    }
    {
        const float2 v1 = *(const float2*)(W1 + 2 * t);   // W1 64x8
        ws[10240 + t] = pk2(v1.x, v1.y);
        const float2 v3 = *(const float2*)(W3 + 2 * t);   // W3 8x64
        ws[10496 + t] = pk2(v3.x, v3.y);
    }
}

template<bool USE_WS>
__global__ __launch_bounds__(512, 4)
void soft_equiv(const float* __restrict__ z,  const float* __restrict__ W1,
                const float* __restrict__ b1, const float* __restrict__ W2,
                const float* __restrict__ b2, const float* __restrict__ W3,
                const float* __restrict__ mixW, const float* __restrict__ gb,
                const unsigned short* __restrict__ wsu,
                float* __restrict__ out)
{
    __shared__ __align__(16) unsigned short zs[ROWS * TD];   // 32 KB bf16 z, swizzled
    __shared__ __align__(16) unsigned short hn[ROWS * NB];   // 2 KB bf16 norms (wave-local)
    __shared__ float sca[ROWS * 9];                           // 4.6 KB (1+softplus)

    const int t    = threadIdx.x;
    const int lane = t & 63;
    const int w    = t >> 6;        // wave id 0..7
    const int hi   = lane >> 4;     // 0..3
    const int lo   = lane & 15;
    const size_t row0 = (size_t)blockIdx.x * ROWS;
    const float* ztile = z + row0 * TD;
    const f32x4 z4 = {0.f, 0.f, 0.f, 0.f};

    // ====== MLP weight fragments (issued first; latency overlaps staging) ======
    bf16x8 a1f[4];
    bf16x8 a2f[4][2];
    bf16x8 a3f[2];
    if constexpr (USE_WS) {
#pragma unroll
        for (int mt = 0; mt < 4; ++mt) {
            U c = {};
            if (hi == 0) c.v = *(const bf16x8*)(wsu + 2 * 10240 + (mt * 16 + lo) * 8);
            a1f[mt] = c.v;
        }
#pragma unroll
        for (int mt = 0; mt < 4; ++mt)
#pragma unroll
            for (int kk = 0; kk < 2; ++kk)
                a2f[mt][kk] = *(const bf16x8*)(wsu + 2 * 8192 + (mt * 16 + lo) * HID + kk * 32 + hi * 8);
#pragma unroll
        for (int kk = 0; kk < 2; ++kk) {
            U c = {};
            if (lo < NB) c.v = *(const bf16x8*)(wsu + 2 * 10496 + lo * HID + kk * 32 + hi * 8);
            a3f[kk] = c.v;
        }
    } else {
#pragma unroll
        for (int mt = 0; mt < 4; ++mt) {
            U c = {};
            if (hi == 0) {
                const float4 x = *(const float4*)(W1 + (mt * 16 + lo) * NB);
                const float4 y = *(const float4*)(W1 + (mt * 16 + lo) * NB + 4);
                c.u[0] = pk2(x.x, x.y); c.u[1] = pk2(x.z, x.w);
                c.u[2] = pk2(y.x, y.y); c.u[3] = pk2(y.z, y.w);
            }
            a1f[mt] = c.v;
        }
#pragma unroll
        for (int mt = 0; mt < 4; ++mt)
#pragma unroll
            for (int kk = 0; kk < 2; ++kk) {
                const float* p = W2 + (mt * 16 + lo) * HID + kk * 32 + hi * 8;
                const float4 x = *(const float4*)p;
                const float4 y = *(const float4*)(p + 4);
                U c;
                c.u[0] = pk2(x.x, x.y); c.u[1] = pk2(x.z, x.w);
                c.u[2] = pk2(y.x, y.y); c.u[3] = pk2(y.z, y.w);
                a2f[mt][kk] = c.v;
            }
#pragma unroll
        for (int kk = 0; kk < 2; ++kk) {
            U c = {};
            if (lo < NB) {
                const float* p = W3 + lo * HID + kk * 32 + hi * 8;
                const float4 x = *(const float4*)p;
                const float4 y = *(const float4*)(p + 4);
                c.u[0] = pk2(x.x, x.y); c.u[1] = pk2(x.z, x.w);
                c.u[2] = pk2(y.x, y.y); c.u[3] = pk2(y.z, y.w);
            }
            a3f[kk] = c.v;
        }
    }
    float4 b1v[4], b2v[4];
#pragma unroll
    for (int mt = 0; mt < 4; ++mt) {
        b1v[mt] = ((const float4*)b1)[mt * 4 + hi];
        b2v[mt] = ((const float4*)b2)[mt * 4 + hi];
    }

    // ====== phase 1: WAVE-LOCAL staging — wave w stages rows 16w..16w+15 ======
#pragma unroll
    for (int i = 0; i < 2; ++i) {
        const int r = 16 * w + i * 8 + (lane >> 3);
        const int b = lane & 7;
        const float* p = ztile + r * TD + b * 16;
        const float4 v0 = *(const float4*)(p);
        const float4 v1 = *(const float4*)(p + 4);
        const float4 v2 = *(const float4*)(p + 8);
        const float4 v3 = *(const float4*)(p + 12);
        const int sw = r & 7;
        uint4 q0 = { pk2(v0.x, v0.y), pk2(v0.z, v0.w), pk2(v1.x, v1.y), pk2(v1.z, v1.w) };
        uint4 q1 = { pk2(v2.x, v2.y), pk2(v2.z, v2.w), pk2(v3.x, v3.y), pk2(v3.z, v3.w) };
        *(uint4*)&zs[r * TD + (((2 * b    ) ^ sw) * 8)] = q0;
        *(uint4*)&zs[r * TD + (((2 * b + 1) ^ sw) * 8)] = q1;
        float s0 = 0.f, s1 = 0.f, s2 = 0.f, s3 = 0.f;
        s0 = fmaf(v0.x, v0.x, s0); s1 = fmaf(v0.y, v0.y, s1);
        s2 = fmaf(v0.z, v0.z, s2); s3 = fmaf(v0.w, v0.w, s3);
        s0 = fmaf(v1.x, v1.x, s0); s1 = fmaf(v1.y, v1.y, s1);
        s2 = fmaf(v1.z, v1.z, s2); s3 = fmaf(v1.w, v1.w, s3);
        s0 = fmaf(v2.x, v2.x, s0); s1 = fmaf(v2.y, v2.y, s1);
        s2 = fmaf(v2.z, v2.z, s2); s3 = fmaf(v2.w, v2.w, s3);
        s0 = fmaf(v3.x, v3.x, s0); s1 = fmaf(v3.y, v3.y, s1);
        s2 = fmaf(v3.z, v3.z, s2); s3 = fmaf(v3.w, v3.w, s3);
        const float nr = sqrtf((s0 + s1) + (s2 + s3)) + 1e-8f;
        __hip_bfloat16 hb = __float2bfloat16(nr);
        unsigned short us; __builtin_memcpy(&us, &hb, 2);
        hn[r * NB + b] = us;
    }
    // NO __syncthreads(): phase 2 reads only wave-local hn rows.

    // ====== phase 2: MLP on MFMA (wave w owns rows 16w..16w+15) ======
    bf16x8 b1f;
    {
        U c = {};
        if (hi == 0) c.v = *(const bf16x8*)&hn[(16 * w + lo) * NB];
        b1f = c.v;
    }

    const int slA = lo + 32 * (hi & 1);
    const int slB = slA + 16;
    const bool selhi = (hi & 2) != 0;

    unsigned pkh[4][2];
#pragma unroll
    for (int mt = 0; mt < 4; ++mt) {
        f32x4 c = __builtin_amdgcn_mfma_f32_16x16x32_bf16(a1f[mt], b1f, z4, 0, 0, 0);
        const float4 bb = b1v[mt];
        const float g0 = gelu_fast(c[0] + bb.x);
        const float g1 = gelu_fast(c[1] + bb.y);
        const float g2 = gelu_fast(c[2] + bb.z);
        const float g3 = gelu_fast(c[3] + bb.w);
        pkh[mt][0] = pk2(g0, g1);
        pkh[mt][1] = pk2(g2, g3);
    }

    bf16x8 b2f[2];
#pragma unroll
    for (int kk = 0; kk < 2; ++kk) {
        U c;
        const unsigned a0 = __shfl((int)pkh[2*kk  ][0], slA, 64);
        const unsigned a1 = __shfl((int)pkh[2*kk  ][1], slA, 64);
        const unsigned a2 = __shfl((int)pkh[2*kk  ][0], slB, 64);
        const unsigned a3 = __shfl((int)pkh[2*kk  ][1], slB, 64);
        const unsigned d0 = __shfl((int)pkh[2*kk+1][0], slA, 64);
        const unsigned d1 = __shfl((int)pkh[2*kk+1][1], slA, 64);
        const unsigned d2 = __shfl((int)pkh[2*kk+1][0], slB, 64);
        const unsigned d3 = __shfl((int)pkh[2*kk+1][1], slB, 64);
        c.u[0] = selhi ? d0 : a0; c.u[1] = selhi ? d1 : a1;
        c.u[2] = selhi ? d2 : a2; c.u[3] = selhi ? d3 : a3;
        b2f[kk] = c.v;
    }

    unsigned pkh2[4][2];
#pragma unroll
    for (int mt = 0; mt < 4; ++mt) {
        f32x4 c = __builtin_amdgcn_mfma_f32_16x16x32_bf16(a2f[mt][0], b2f[0], z4, 0, 0, 0);
        c = __builtin_amdgcn_mfma_f32_16x16x32_bf16(a2f[mt][1], b2f[1], c, 0, 0, 0);
        const float4 bb = b2v[mt];
        const float g0 = gelu_fast(c[0] + bb.x);
        const float g1 = gelu_fast(c[1] + bb.y);
        const float g2 = gelu_fast(c[2] + bb.z);
        const float g3 = gelu_fast(c[3] + bb.w);
        pkh2[mt][0] = pk2(g0, g1);
        pkh2[mt][1] = pk2(g2, g3);
    }

    {
        U c0, c1;
#pragma unroll
        for (int kk = 0; kk < 2; ++kk) {
            const unsigned a0 = __shfl((int)pkh2[2*kk  ][0], slA, 64);
            const unsigned a1 = __shfl((int)pkh2[2*kk  ][1], slA, 64);
            const unsigned a2 = __shfl((int)pkh2[2*kk  ][0], slB, 64);
            const unsigned a3 = __shfl((int)pkh2[2*kk  ][1], slB, 64);
            const unsigned d0 = __shfl((int)pkh2[2*kk+1][0], slA, 64);
            const unsigned d1 = __shfl((int)pkh2[2*kk+1][1], slA, 64);
            const unsigned d2 = __shfl((int)pkh2[2*kk+1][0], slB, 64);
            const unsigned d3 = __shfl((int)pkh2[2*kk+1][1], slB, 64);
            if (kk == 0) {
                c0.u[0] = selhi ? d0 : a0; c0.u[1] = selhi ? d1 : a1;
                c0.u[2] = selhi ? d2 : a2; c0.u[3] = selhi ? d3 : a3;
            } else {
                c1.u[0] = selhi ? d0 : a0; c1.u[1] = selhi ? d1 : a1;
                c1.u[2] = selhi ? d2 : a2; c1.u[3] = selhi ? d3 : a3;
            }
        }
        f32x4 s3 = __builtin_amdgcn_mfma_f32_16x16x32_bf16(a3f[0], c0.v, z4, 0, 0, 0);
        s3 = __builtin_amdgcn_mfma_f32_16x16x32_bf16(a3f[1], c1.v, s3, 0, 0, 0);
        if (hi < 2) {
            const int r = 16 * w + lo;
#pragma unroll
            for (int e = 0; e < 4; ++e) {
                const float x  = s3[e];
                const float sp = fmaxf(x, 0.f) +
                    0.69314718f * __builtin_amdgcn_logf(
                        1.0f + __builtin_amdgcn_exp2f(-fabsf(x) * 1.44269504f));
                sca[r * 9 + hi * 4 + e] = 1.0f + sp;
            }
        }
    }

    // ====== mixed-einsum B fragments: wave w owns col tile (w>>1)*32..+31 ======
    bf16x8 bfr[2][4];
#pragma unroll
    for (int n = 0; n < 2; ++n) {
        const int col = (w >> 1) * 32 + n * 16 + lo;
#pragma unroll
        for (int kk = 0; kk < 4; ++kk) {
            if constexpr (USE_WS) {
                bfr[n][kk] = *(const bf16x8*)(wsu + col * TD + kk * 32 + hi * 8);
            } else {
                const int k0 = kk * 32 + hi * 8;
                const float* p = mixW + (col >> 4) * 2048 + (k0 >> 4) * 256
                                      + (col & 15) * 16 + (k0 & 15);
                const float4 x = *(const float4*)p;
                const float4 y = *(const float4*)(p + 4);
                U c;
                c.u[0] = pk2(x.x, x.y); c.u[1] = pk2(x.z, x.w);
                c.u[2] = pk2(y.x, y.y); c.u[3] = pk2(y.z, y.w);
                bfr[n][kk] = c.v;
            }
        }
    }
    const float g0 = 1.f / (1.f + __builtin_amdgcn_exp2f(-gb[2 * (w >> 1) + 0] * 1.44269504f));
    const float g1 = 1.f / (1.f + __builtin_amdgcn_exp2f(-gb[2 * (w >> 1) + 1] * 1.44269504f));

    __syncthreads();   // zs (all waves) + sca complete

    // ====== phase 3: wave w -> rows (w&1)*64..+63 x cols (w>>1)*32..+31 ======
    // Both n-halves of each 128B line stored back-to-back -> full-line NT writes.
    const int rb = (w & 1) * 64;
#pragma unroll
    for (int mt = 0; mt < 4; ++mt) {
        const int ar = rb + mt * 16 + lo;
        bf16x8 af[4];
#pragma unroll
        for (int kk = 0; kk < 4; ++kk) {
            const int slot = (kk * 4 + hi) ^ (ar & 7);
            af[kk] = *(const bf16x8*)&zs[ar * TD + slot * 8];
        }
        f32x4 acc0 = z4, acc1 = z4;
#pragma unroll
        for (int kk = 0; kk < 4; ++kk)
            acc0 = __builtin_amdgcn_mfma_f32_16x16x32_bf16(af[kk], bfr[0][kk], acc0, 0, 0, 0);
#pragma unroll
        for (int kk = 0; kk < 4; ++kk)
            acc1 = __builtin_amdgcn_mfma_f32_16x16x32_bf16(af[kk], bfr[1][kk], acc1, 0, 0, 0);

        const int col0 = (w >> 1) * 32 + lo;
        const int col1 = col0 + 16;
        const int sl0 = col0 >> 3, cw0 = col0 & 7;
        const int sl1 = col1 >> 3, cw1 = col1 & 7;
        const int nb0 = (w >> 1) * 2;
#pragma unroll
        for (int e = 0; e < 4; ++e) {
            const int rr = rb + mt * 16 + hi * 4 + e;
            const int swr = rr & 7;
            const float sc0 = sca[rr * 9 + nb0 + 0];
            const float sc1 = sca[rr * 9 + nb0 + 1];
            const float zv0 = __uint_as_float(
                (unsigned int)zs[rr * TD + ((sl0 ^ swr) * 8) + cw0] << 16);
            const float zv1 = __uint_as_float(
                (unsigned int)zs[rr * TD + ((sl1 ^ swr) * 8) + cw1] << 16);
            float* orow = &out[(row0 + rr) * TD];
            __builtin_nontemporal_store(fmaf(zv0, sc0, g0 * acc0[e]), orow + col0);
            __builtin_nontemporal_store(fmaf(zv1, sc1, g1 * acc1[e]), orow + col1);
        }
    }
}

extern "C" void kernel_launch(void* const* d_in, const int* in_sizes, int n_in,
                              void* d_out, int out_size, void* d_ws, size_t ws_size,
                              hipStream_t stream) {
    const float* z    = (const float*)d_in[0];
    const float* W1   = (const float*)d_in[1];
    const float* b1   = (const float*)d_in[2];
    const float* W2   = (const float*)d_in[3];
    const float* b2   = (const float*)d_in[4];
    const float* W3   = (const float*)d_in[5];
    const float* mixW = (const float*)d_in[6];
    const float* gb   = (const float*)d_in[7];
    float* out = (float*)d_out;

    const int B = in_sizes[0] / TD;
    if (ws_size >= WS_NEED_BYTES && d_ws != nullptr) {
        cvt_weights<<<1, 256, 0, stream>>>(W1, W2, W3, mixW, (unsigned*)d_ws);
        soft_equiv<true><<<B / ROWS, 512, 0, stream>>>(
            z, W1, b1, W2, b2, W3, mixW, gb, (const unsigned short*)d_ws, out);
    } else {
        soft_equiv<false><<<B / ROWS, 512, 0, stream>>>(
            z, W1, b1, W2, b2, W3, mixW, gb, nullptr, out);
    }
}

// Round 22
// 110.135 us; speedup vs baseline: 1.1883x; 1.1883x over previous
//
#include <hip/hip_runtime.h>
#include <hip/hip_bf16.h>

constexpr int NB  = 8;
constexpr int TD  = 128;
constexpr int HID = 64;
constexpr int ROWS = 128;

typedef __attribute__((ext_vector_type(8))) short bf16x8;
typedef __attribute__((ext_vector_type(4))) float f32x4;

union U { unsigned u[4]; bf16x8 v; };

__device__ __forceinline__ unsigned int pk2(float a, float b) {
    __hip_bfloat162 h = __float22bfloat162_rn(float2{a, b});   // v_cvt_pk_bf16_f32 (RNE)
    unsigned int u; __builtin_memcpy(&u, &h, 4); return u;
}

// branch-free GELU: erf via Abramowitz-Stegun 7.1.26 (|err| < 1.5e-7)
__device__ __forceinline__ float gelu_fast(float x) {
    const float u = x * 0.70710678118f;
    const float a = fabsf(u);
    const float t = __builtin_amdgcn_rcpf(fmaf(0.3275911f, a, 1.0f));
    float p = fmaf(t, 1.061405429f, -1.453152027f);
    p = fmaf(t, p, 1.421413741f);
    p = fmaf(t, p, -0.284496736f);
    p = fmaf(t, p, 0.254829592f);
    p = p * t;
    const float e  = __builtin_amdgcn_exp2f(-a * a * 1.44269504f);
    const float pe = p * e;
    const float s  = (u >= 0.f) ? (2.0f - pe) : pe;   // 1 + erf(u)
    return 0.5f * x * s;
}

// ws layout (u32 pairs): [0,8192) mixW ; [8192,10240) W2 ; [10240,10496) W1 ; [10496,10752) W3
constexpr size_t WS_NEED_BYTES = 10752 * 4;

__global__ __launch_bounds__(256, 1)
void cvt_weights(const float* __restrict__ W1, const float* __restrict__ W2,
                 const float* __restrict__ W3, const float* __restrict__ mixW,
                 unsigned* __restrict__ ws)
{
    const int t = threadIdx.x;
#pragma unroll
    for (int i = 0; i < 32; ++i) {                 // mixW -> Wm[c][f], c=i*16+d, f=j*16+k
        const int p = t + i * 256;
        const int o = 2 * p;
        const int c = o >> 7, f = o & 127;
        const int ii = c >> 4, d = c & 15, j = f >> 4, k = f & 15;
        const float2 v = *(const float2*)(mixW + ii * 2048 + j * 256 + d * 16 + k);
        ws[p] = pk2(v.x, v.y);
    }
#pragma unroll
    for (int i = 0; i < 8; ++i) {                  // W2 row-major 64x64
        const int p = t + i * 256;
        const float2 v = *(const float2*)(W2 + 2 * p);
        ws[8192 + p] = pk2(v.x, v.y);
    }
    {
        const float2 v1 = *(const float2*)(W1 + 2 * t);   // W1 64x8
        ws[10240 + t] = pk2(v1.x, v1.y);
        const float2 v3 = *(const float2*)(W3 + 2 * t);   // W3 8x64
        ws[10496 + t] = pk2(v3.x, v3.y);
    }
}

template<bool USE_WS>
__global__ __launch_bounds__(256, 4)
void soft_equiv(const float* __restrict__ z,  const float* __restrict__ W1,
                const float* __restrict__ b1, const float* __restrict__ W2,
                const float* __restrict__ b2, const float* __restrict__ W3,
                const float* __restrict__ mixW, const float* __restrict__ gb,
                const unsigned short* __restrict__ wsu,
                float* __restrict__ out)
{
    __shared__ __align__(16) unsigned short zs[ROWS * TD];   // 32 KB bf16 z, swizzled
    __shared__ __align__(16) unsigned short hn[ROWS * NB];   // 2 KB bf16 norms (wave-local)
    __shared__ float sca[ROWS * 9];                           // 4.6 KB (1+softplus)

    const int t    = threadIdx.x;
    const int lane = t & 63;
    const int w    = t >> 6;        // wave id 0..3
    const int hi   = lane >> 4;     // 0..3
    const int lo   = lane & 15;
    const size_t row0 = (size_t)blockIdx.x * ROWS;
    const float* ztile = z + row0 * TD;
    const f32x4 z4 = {0.f, 0.f, 0.f, 0.f};

    // ====== MLP weight fragments (issued first; latency overlaps staging) ======
    bf16x8 a1f[4];
    bf16x8 a2f[4][2];
    bf16x8 a3f[2];
    if constexpr (USE_WS) {
#pragma unroll
        for (int mt = 0; mt < 4; ++mt) {
            U c = {};
            if (hi == 0) c.v = *(const bf16x8*)(wsu + 2 * 10240 + (mt * 16 + lo) * 8);
            a1f[mt] = c.v;
        }
#pragma unroll
        for (int mt = 0; mt < 4; ++mt)
#pragma unroll
            for (int kk = 0; kk < 2; ++kk)
                a2f[mt][kk] = *(const bf16x8*)(wsu + 2 * 8192 + (mt * 16 + lo) * HID + kk * 32 + hi * 8);
#pragma unroll
        for (int kk = 0; kk < 2; ++kk) {
            U c = {};
            if (lo < NB) c.v = *(const bf16x8*)(wsu + 2 * 10496 + lo * HID + kk * 32 + hi * 8);
            a3f[kk] = c.v;
        }
    } else {
#pragma unroll
        for (int mt = 0; mt < 4; ++mt) {
            U c = {};
            if (hi == 0) {
                const float4 x = *(const float4*)(W1 + (mt * 16 + lo) * NB);
                const float4 y = *(const float4*)(W1 + (mt * 16 + lo) * NB + 4);
                c.u[0] = pk2(x.x, x.y); c.u[1] = pk2(x.z, x.w);
                c.u[2] = pk2(y.x, y.y); c.u[3] = pk2(y.z, y.w);
            }
            a1f[mt] = c.v;
        }
#pragma unroll
        for (int mt = 0; mt < 4; ++mt)
#pragma unroll
            for (int kk = 0; kk < 2; ++kk) {
                const float* p = W2 + (mt * 16 + lo) * HID + kk * 32 + hi * 8;
                const float4 x = *(const float4*)p;
                const float4 y = *(const float4*)(p + 4);
                U c;
                c.u[0] = pk2(x.x, x.y); c.u[1] = pk2(x.z, x.w);
                c.u[2] = pk2(y.x, y.y); c.u[3] = pk2(y.z, y.w);
                a2f[mt][kk] = c.v;
            }
#pragma unroll
        for (int kk = 0; kk < 2; ++kk) {
            U c = {};
            if (lo < NB) {
                const float* p = W3 + lo * HID + kk * 32 + hi * 8;
                const float4 x = *(const float4*)p;
                const float4 y = *(const float4*)(p + 4);
                c.u[0] = pk2(x.x, x.y); c.u[1] = pk2(x.z, x.w);
                c.u[2] = pk2(y.x, y.y); c.u[3] = pk2(y.z, y.w);
            }
            a3f[kk] = c.v;
        }
    }
    float4 b1v[4], b2v[4];
#pragma unroll
    for (int mt = 0; mt < 4; ++mt) {
        b1v[mt] = ((const float4*)b1)[mt * 4 + hi];
        b2v[mt] = ((const float4*)b2)[mt * 4 + hi];
    }

    // ====== phase 1: WAVE-LOCAL staging — wave w stages its own MLP rows ======
    // Wave w covers rows 32w..32w+31 (the exact rows its phase-2 MLP consumes),
    // so hn production->consumption is wave-local and needs NO block barrier.
#pragma unroll
    for (int i = 0; i < 4; ++i) {
        const int r = 32 * w + i * 8 + (lane >> 3);   // (row, bundle), wave-local rows
        const int b = lane & 7;
        const float* p = ztile + r * TD + b * 16;
        const float4 v0 = *(const float4*)(p);
        const float4 v1 = *(const float4*)(p + 4);
        const float4 v2 = *(const float4*)(p + 8);
        const float4 v3 = *(const float4*)(p + 12);
        const int sw = r & 7;
        uint4 q0 = { pk2(v0.x, v0.y), pk2(v0.z, v0.w), pk2(v1.x, v1.y), pk2(v1.z, v1.w) };
        uint4 q1 = { pk2(v2.x, v2.y), pk2(v2.z, v2.w), pk2(v3.x, v3.y), pk2(v3.z, v3.w) };
        *(uint4*)&zs[r * TD + (((2 * b    ) ^ sw) * 8)] = q0;
        *(uint4*)&zs[r * TD + (((2 * b + 1) ^ sw) * 8)] = q1;
        float s0 = 0.f, s1 = 0.f, s2 = 0.f, s3 = 0.f;
        s0 = fmaf(v0.x, v0.x, s0); s1 = fmaf(v0.y, v0.y, s1);
        s2 = fmaf(v0.z, v0.z, s2); s3 = fmaf(v0.w, v0.w, s3);
        s0 = fmaf(v1.x, v1.x, s0); s1 = fmaf(v1.y, v1.y, s1);
        s2 = fmaf(v1.z, v1.z, s2); s3 = fmaf(v1.w, v1.w, s3);
        s0 = fmaf(v2.x, v2.x, s0); s1 = fmaf(v2.y, v2.y, s1);
        s2 = fmaf(v2.z, v2.z, s2); s3 = fmaf(v2.w, v2.w, s3);
        s0 = fmaf(v3.x, v3.x, s0); s1 = fmaf(v3.y, v3.y, s1);
        s2 = fmaf(v3.z, v3.z, s2); s3 = fmaf(v3.w, v3.w, s3);
        const float nr = sqrtf((s0 + s1) + (s2 + s3)) + 1e-8f;
        __hip_bfloat16 hb = __float2bfloat16(nr);
        unsigned short us; __builtin_memcpy(&us, &hb, 2);
        hn[r * NB + b] = us;
    }
    // NO __syncthreads() here: phase 2 reads only wave-local hn rows.

    // ====== phase 2: MLP on MFMA (wave w owns rows 32w..32w+31) ======
    bf16x8 b1f[2];
#pragma unroll
    for (int nt = 0; nt < 2; ++nt) {
        U c = {};
        if (hi == 0)
            c.v = *(const bf16x8*)&hn[(32 * w + nt * 16 + lo) * NB];
        b1f[nt] = c.v;
    }

    const int slA = lo + 32 * (hi & 1);
    const int slB = slA + 16;
    const bool selhi = (hi & 2) != 0;

    unsigned pkh[2][4][2];
#pragma unroll
    for (int nt = 0; nt < 2; ++nt)
#pragma unroll
        for (int mt = 0; mt < 4; ++mt) {
            f32x4 c = __builtin_amdgcn_mfma_f32_16x16x32_bf16(a1f[mt], b1f[nt], z4, 0, 0, 0);
            const float4 bb = b1v[mt];
            const float g0 = gelu_fast(c[0] + bb.x);
            const float g1 = gelu_fast(c[1] + bb.y);
            const float g2 = gelu_fast(c[2] + bb.z);
            const float g3 = gelu_fast(c[3] + bb.w);
            pkh[nt][mt][0] = pk2(g0, g1);
            pkh[nt][mt][1] = pk2(g2, g3);
        }

    bf16x8 b2f[2][2];
#pragma unroll
    for (int nt = 0; nt < 2; ++nt)
#pragma unroll
        for (int kk = 0; kk < 2; ++kk) {
            U c;
            const unsigned a0 = __shfl((int)pkh[nt][2*kk  ][0], slA, 64);
            const unsigned a1 = __shfl((int)pkh[nt][2*kk  ][1], slA, 64);
            const unsigned a2 = __shfl((int)pkh[nt][2*kk  ][0], slB, 64);
            const unsigned a3 = __shfl((int)pkh[nt][2*kk  ][1], slB, 64);
            const unsigned d0 = __shfl((int)pkh[nt][2*kk+1][0], slA, 64);
            const unsigned d1 = __shfl((int)pkh[nt][2*kk+1][1], slA, 64);
            const unsigned d2 = __shfl((int)pkh[nt][2*kk+1][0], slB, 64);
            const unsigned d3 = __shfl((int)pkh[nt][2*kk+1][1], slB, 64);
            c.u[0] = selhi ? d0 : a0; c.u[1] = selhi ? d1 : a1;
            c.u[2] = selhi ? d2 : a2; c.u[3] = selhi ? d3 : a3;
            b2f[nt][kk] = c.v;
        }

    unsigned pkh2[2][4][2];
#pragma unroll
    for (int nt = 0; nt < 2; ++nt)
#pragma unroll
        for (int mt = 0; mt < 4; ++mt) {
            f32x4 c = __builtin_amdgcn_mfma_f32_16x16x32_bf16(a2f[mt][0], b2f[nt][0], z4, 0, 0, 0);
            c = __builtin_amdgcn_mfma_f32_16x16x32_bf16(a2f[mt][1], b2f[nt][1], c, 0, 0, 0);
            const float4 bb = b2v[mt];
            const float g0 = gelu_fast(c[0] + bb.x);
            const float g1 = gelu_fast(c[1] + bb.y);
            const float g2 = gelu_fast(c[2] + bb.z);
            const float g3 = gelu_fast(c[3] + bb.w);
            pkh2[nt][mt][0] = pk2(g0, g1);
            pkh2[nt][mt][1] = pk2(g2, g3);
        }

#pragma unroll
    for (int nt = 0; nt < 2; ++nt) {
        U c0, c1;
#pragma unroll
        for (int kk = 0; kk < 2; ++kk) {
            const unsigned a0 = __shfl((int)pkh2[nt][2*kk  ][0], slA, 64);
            const unsigned a1 = __shfl((int)pkh2[nt][2*kk  ][1], slA, 64);
            const unsigned a2 = __shfl((int)pkh2[nt][2*kk  ][0], slB, 64);
            const unsigned a3 = __shfl((int)pkh2[nt][2*kk  ][1], slB, 64);
            const unsigned d0 = __shfl((int)pkh2[nt][2*kk+1][0], slA, 64);
            const unsigned d1 = __shfl((int)pkh2[nt][2*kk+1][1], slA, 64);
            const unsigned d2 = __shfl((int)pkh2[nt][2*kk+1][0], slB, 64);
            const unsigned d3 = __shfl((int)pkh2[nt][2*kk+1][1], slB, 64);
            if (kk == 0) {
                c0.u[0] = selhi ? d0 : a0; c0.u[1] = selhi ? d1 : a1;
                c0.u[2] = selhi ? d2 : a2; c0.u[3] = selhi ? d3 : a3;
            } else {
                c1.u[0] = selhi ? d0 : a0; c1.u[1] = selhi ? d1 : a1;
                c1.u[2] = selhi ? d2 : a2; c1.u[3] = selhi ? d3 : a3;
            }
        }
        f32x4 s3 = __builtin_amdgcn_mfma_f32_16x16x32_bf16(a3f[0], c0.v, z4, 0, 0, 0);
        s3 = __builtin_amdgcn_mfma_f32_16x16x32_bf16(a3f[1], c1.v, s3, 0, 0, 0);
        if (hi < 2) {
            const int r = 32 * w + nt * 16 + lo;
#pragma unroll
            for (int e = 0; e < 4; ++e) {
                const float x  = s3[e];
                const float sp = fmaxf(x, 0.f) +
                    0.69314718f * __builtin_amdgcn_logf(
                        1.0f + __builtin_amdgcn_exp2f(-fabsf(x) * 1.44269504f));
                sca[r * 9 + hi * 4 + e] = 1.0f + sp;
            }
        }
    }

    // ====== mixed-einsum B fragments ======
    bf16x8 bfr[2][4];
#pragma unroll
    for (int n = 0; n < 2; ++n) {
        const int col = w * 32 + n * 16 + lo;
#pragma unroll
        for (int kk = 0; kk < 4; ++kk) {
            if constexpr (USE_WS) {
                bfr[n][kk] = *(const bf16x8*)(wsu + col * TD + kk * 32 + hi * 8);
            } else {
                const int k0 = kk * 32 + hi * 8;
                const float* p = mixW + (col >> 4) * 2048 + (k0 >> 4) * 256
                                      + (col & 15) * 16 + (k0 & 15);
                const float4 x = *(const float4*)p;
                const float4 y = *(const float4*)(p + 4);
                U c;
                c.u[0] = pk2(x.x, x.y); c.u[1] = pk2(x.z, x.w);
                c.u[2] = pk2(y.x, y.y); c.u[3] = pk2(y.z, y.w);
                bfr[n][kk] = c.v;
            }
        }
    }
    const float g0 = 1.f / (1.f + __builtin_amdgcn_exp2f(-gb[2 * w + 0] * 1.44269504f));
    const float g1 = 1.f / (1.f + __builtin_amdgcn_exp2f(-gb[2 * w + 1] * 1.44269504f));

    __syncthreads();   // zs (all waves) + sca complete

    // ====== phase 3: mixed einsum MFMA + fused epilogue ======
    // Both n-halves of each 128B line stored back-to-back -> full-line NT writes.
#pragma unroll
    for (int m = 0; m < 8; ++m) {
        const int ar = m * 16 + lo;
        bf16x8 af[4];
#pragma unroll
        for (int kk = 0; kk < 4; ++kk) {
            const int slot = (kk * 4 + hi) ^ (ar & 7);
            af[kk] = *(const bf16x8*)&zs[ar * TD + slot * 8];
        }
        f32x4 acc0 = z4, acc1 = z4;
#pragma unroll
        for (int kk = 0; kk < 4; ++kk)
            acc0 = __builtin_amdgcn_mfma_f32_16x16x32_bf16(af[kk], bfr[0][kk], acc0, 0, 0, 0);
#pragma unroll
        for (int kk = 0; kk < 4; ++kk)
            acc1 = __builtin_amdgcn_mfma_f32_16x16x32_bf16(af[kk], bfr[1][kk], acc1, 0, 0, 0);

        const int col0 = w * 32 + lo;
        const int col1 = col0 + 16;
        const int sl0 = col0 >> 3, cw0 = col0 & 7;
        const int sl1 = col1 >> 3, cw1 = col1 & 7;
#pragma unroll
        for (int e = 0; e < 4; ++e) {
            const int rr = m * 16 + hi * 4 + e;
            const int swr = rr & 7;
            const float sc0 = sca[rr * 9 + 2 * w + 0];
            const float sc1 = sca[rr * 9 + 2 * w + 1];
            const float zv0 = __uint_as_float(
                (unsigned int)zs[rr * TD + ((sl0 ^ swr) * 8) + cw0] << 16);
            const float zv1 = __uint_as_float(
                (unsigned int)zs[rr * TD + ((sl1 ^ swr) * 8) + cw1] << 16);
            float* orow = &out[(row0 + rr) * TD];
            __builtin_nontemporal_store(fmaf(zv0, sc0, g0 * acc0[e]), orow + col0);
            __builtin_nontemporal_store(fmaf(zv1, sc1, g1 * acc1[e]), orow + col1);
        }
    }
}

extern "C" void kernel_launch(void* const* d_in, const int* in_sizes, int n_in,
                              void* d_out, int out_size, void* d_ws, size_t ws_size,
                              hipStream_t stream) {
    const float* z    = (const float*)d_in[0];
    const float* W1   = (const float*)d_in[1];
    const float* b1   = (const float*)d_in[2];
    const float* W2   = (const float*)d_in[3];
    const float* b2   = (const float*)d_in[4];
    const float* W3   = (const float*)d_in[5];
    const float* mixW = (const float*)d_in[6];
    const float* gb   = (const float*)d_in[7];
    float* out = (float*)d_out;

    const int B = in_sizes[0] / TD;
    if (ws_size >= WS_NEED_BYTES && d_ws != nullptr) {
        cvt_weights<<<1, 256, 0, stream>>>(W1, W2, W3, mixW, (unsigned*)d_ws);
        soft_equiv<true><<<B / ROWS, 256, 0, stream>>>(
            z, W1, b1, W2, b2, W3, mixW, gb, (const unsigned short*)d_ws, out);
    } else {
        soft_equiv<false><<<B / ROWS, 256, 0, stream>>>(
            z, W1, b1, W2, b2, W3, mixW, gb, nullptr, out);
    }
}